// Round 10
// baseline (62.026 us; speedup 1.0000x reference)
//
#include <hip/hip_runtime.h>
#include <cmath>

// Problem constants (fixed by the reference)
#define BB   64
#define TT   4096
#define DD1  256
#define DD2  128
#define UU   64
#define NT   16      // T tiles per batch row
#define TTILE 256    // rows per block
#define CH   32      // rows per chunk (staged in LDS)
#define NCH  8
#define THREADS 256

// A rows: 264 fp16 (=528 B): 256 data + 8 pad -> 4-dword bank rotation/row.
#define ROWB 528

// LDS byte offsets (static shared, 34.8 KB -> 4 blocks/CU at (256,4))
#define A0_OFF   0        // A buf0 [32][264] fp16 = 16896 B
#define A1_OFF   16896    // A buf1
#define BIAS_OFF 33792    // 64 f32
#define LOGP_OFF 34048    // 128 f32 logit partials (4 u-groups x 32 rows)
#define RED_OFF  34560    // 256 f32 (bias partials)
#define LDS_BYTES 35584

typedef _Float16 fp16x8 __attribute__((ext_vector_type(8)));
typedef float    f32x4  __attribute__((ext_vector_type(4)));

__device__ __forceinline__ float tanh_fast(float x) {
    float ax = fabsf(x);
    float e  = __expf(-2.0f * ax);
    float t  = __fdividef(1.0f - e, 1.0f + e);
    return x < 0.0f ? -t : t;
}

// 8 f32 -> fp16x8 (RNE per element)
__device__ __forceinline__ fp16x8 cvt8(float4 a, float4 b) {
    fp16x8 v;
    v[0] = (_Float16)a.x; v[1] = (_Float16)a.y; v[2] = (_Float16)a.z; v[3] = (_Float16)a.w;
    v[4] = (_Float16)b.x; v[5] = (_Float16)b.y; v[6] = (_Float16)b.z; v[7] = (_Float16)b.w;
    return v;
}

__global__ __launch_bounds__(THREADS, 4)   // 4 waves/EU -> 4 blocks/CU, VGPR cap 128
void caa_main(const float* __restrict__ seq, const float* __restrict__ ctx,
              const float* __restrict__ W1, const float* __restrict__ W2,
              float* __restrict__ part) {
    __shared__ __align__(16) char smem[LDS_BYTES];
    float* fbias = (float*)(smem + BIAS_OFF);
    float* flogp = (float*)(smem + LOGP_OFF);
    float* fred  = (float*)(smem + RED_OFF);

    const int tid = threadIdx.x;
    const int bx  = blockIdx.x;
    const int b    = bx >> 4, tile = bx & 15;
    const int w    = tid >> 6, l = tid & 63;
    const int l15  = l & 15,  kg = l >> 4;     // MFMA input: row/col = l15, k-octet = kg
    const int s    = tid >> 5, q31 = tid & 31; // staging: row-slot s, dim-octet q31
    const int dq   = tid & 63, to = tid >> 6;  // accum: dim-quad dq, row-octet to (== w)
    const int srow = l & 31;                   // softmax row owned by this lane

    const float* seqbase = seq + ((size_t)b * TT + (size_t)tile * TTILE) * DD1;

    // ---- chunk 0 global prefetch (8 float4 = 32 VGPR) ----
    float4 pf[8];
    {
        const float4* g = (const float4*)seqbase;
        #pragma unroll
        for (int j = 0; j < 4; ++j) {
            pf[2*j]   = g[j*512 + 2*tid];
            pf[2*j+1] = g[j*512 + 2*tid + 1];
        }
    }

    // ---- B-frags (W1_seq, fp16): 1 u-group of 16 per wave, 32 VGPR ----
    const int u0g = w * 16 + l15;
    fp16x8 bf[8];
    #pragma unroll
    for (int ks = 0; ks < 8; ++ks) {
        const int kb = ks * 32 + kg * 8;
        float4 x0, x1;
        x0.x = W1[(kb+0)*UU + u0g]; x0.y = W1[(kb+1)*UU + u0g];
        x0.z = W1[(kb+2)*UU + u0g]; x0.w = W1[(kb+3)*UU + u0g];
        x1.x = W1[(kb+4)*UU + u0g]; x1.y = W1[(kb+5)*UU + u0g];
        x1.z = W1[(kb+6)*UU + u0g]; x1.w = W1[(kb+7)*UU + u0g];
        bf[ks] = cvt8(x0, x1);
    }

    // ---- bias partials: 4 c-chunks x 64 u ----
    {
        const int cq = tid >> 6;
        float sacc = 0.f;
        const float* cb = ctx + b * DD2 + cq * 32;
        const float* wb = W1 + (size_t)(DD1 + cq * 32) * UU + l;
        #pragma unroll
        for (int c = 0; c < 32; ++c) sacc = fmaf(cb[c], wb[c * UU], sacc);
        fred[cq * 64 + l] = sacc;
    }
    __syncthreads();
    if (tid < 64) {
        fbias[tid] = fred[tid] + fred[64 + tid] + fred[128 + tid] + fred[192 + tid];
    }
    // ---- chunk 0 -> A0 (waits chunk-0 loads), then issue chunk 1 -> pf ----
    #pragma unroll
    for (int j = 0; j < 4; ++j)
        *(fp16x8*)(smem + A0_OFF + (8*j + s) * ROWB + q31 * 16) = cvt8(pf[2*j], pf[2*j+1]);
    {
        const float4* g = (const float4*)(seqbase + (size_t)CH * DD1);
        #pragma unroll
        for (int j = 0; j < 4; ++j) {
            pf[2*j]   = g[j*512 + 2*tid];
            pf[2*j+1] = g[j*512 + 2*tid + 1];
        }
    }
    __syncthreads();

    const float bias0 = fbias[u0g];
    const float w20   = W2[u0g];
    const int aB0 = (     l15) * ROWB + kg * 16;   // m-frag 0 A byte base
    const int aB1 = (16 + l15) * ROWB + kg * 16;   // m-frag 1

    float4 accA = make_float4(0.f, 0.f, 0.f, 0.f); // dims 4dq..+3, rows to*8..+7 partial
    float  mreg = -INFINITY, lreg = 0.f;           // online-softmax state (uniform/thread)

    for (int c = 0; c < NCH; ++c) {
        const char* bufc = smem + ((c & 1) ? A1_OFF : A0_OFF);
        char*       bufn = smem + ((c & 1) ? A0_OFF : A1_OFF);
        // ---- TOP: stage chunk c+1 (in pf) -> bufn; then issue chunk c+2 -> pf.
        // bufn's last reader was iter c-1's accum (fenced by barrier C).
        // Loads issued here stay in flight for a FULL iteration -> continuous
        // HBM demand from every resident block.
        if (c < NCH - 1) {
            #pragma unroll
            for (int j = 0; j < 4; ++j)
                *(fp16x8*)(bufn + (8*j + s) * ROWB + q31 * 16) = cvt8(pf[2*j], pf[2*j+1]);
        }
        if (c < NCH - 2) {
            const float4* g = (const float4*)(seqbase + (size_t)(c + 2) * CH * DD1);
            #pragma unroll
            for (int j = 0; j < 4; ++j) {
                pf[2*j]   = g[j*512 + 2*tid];
                pf[2*j+1] = g[j*512 + 2*tid + 1];
            }
        }
        // ---- fp16 MFMA GEMM: 32 rows x 16 u per wave, K=256, 16 MFMA ----
        f32x4 acc0 = {0.f,0.f,0.f,0.f}, acc1 = {0.f,0.f,0.f,0.f};
        #pragma unroll
        for (int ks = 0; ks < 8; ++ks) {
            fp16x8 ah0 = *(const fp16x8*)(bufc + aB0 + ks * 64);
            fp16x8 ah1 = *(const fp16x8*)(bufc + aB1 + ks * 64);
            acc0 = __builtin_amdgcn_mfma_f32_16x16x32_f16(ah0, bf[ks], acc0, 0, 0, 0);
            acc1 = __builtin_amdgcn_mfma_f32_16x16x32_f16(ah1, bf[ks], acc1, 0, 0, 0);
        }
        // ---- epilogue: tanh + W2 dot; reduce over the 16 u lanes ----
        float lp0[4], lp1[4];
        #pragma unroll
        for (int r = 0; r < 4; ++r) {
            float p0 = tanh_fast(acc0[r] + bias0) * w20;
            float p1 = tanh_fast(acc1[r] + bias0) * w20;
            p0 += __shfl_xor(p0, 1, 64);
            p1 += __shfl_xor(p1, 1, 64);
            p0 += __shfl_xor(p0, 2, 64);
            p1 += __shfl_xor(p1, 2, 64);
            p0 += __shfl_xor(p0, 4, 64);
            p1 += __shfl_xor(p1, 4, 64);
            p0 += __shfl_xor(p0, 8, 64);
            p1 += __shfl_xor(p1, 8, 64);
            lp0[r] = p0; lp1[r] = p1;
        }
        if (l15 == 0) {      // C/D row = kg*4 + r within m-frag (verified layout)
            #pragma unroll
            for (int r = 0; r < 4; ++r) {
                flogp[w * 32 +      kg * 4 + r] = lp0[r];
                flogp[w * 32 + 16 + kg * 4 + r] = lp1[r];
            }
        }
        __syncthreads();                        // (A) logit partials + bufn visible
        // ---- softmax over 32 rows, computed redundantly by EVERY wave ----
        float wv, rsc;
        {
            float lg = flogp[srow] + flogp[32 + srow] + flogp[64 + srow] + flogp[96 + srow];
            float mx = lg;
            mx = fmaxf(mx, __shfl_xor(mx, 1, 32));
            mx = fmaxf(mx, __shfl_xor(mx, 2, 32));
            mx = fmaxf(mx, __shfl_xor(mx, 4, 32));
            mx = fmaxf(mx, __shfl_xor(mx, 8, 32));
            mx = fmaxf(mx, __shfl_xor(mx, 16, 32));
            float mnew = fmaxf(mreg, mx);
            rsc = __expf(mreg - mnew);          // first chunk: exp(-inf)=0
            wv  = __expf(lg - mnew);
            float ss = wv;
            ss += __shfl_xor(ss, 1, 32);
            ss += __shfl_xor(ss, 2, 32);
            ss += __shfl_xor(ss, 4, 32);
            ss += __shfl_xor(ss, 8, 32);
            ss += __shfl_xor(ss, 16, 32);
            mreg = mnew;
            lreg = lreg * rsc + ss;
        }
        // ---- weighted accumulation from current fp16 tile (w via shfl) ----
        {
            accA.x *= rsc; accA.y *= rsc; accA.z *= rsc; accA.w *= rsc;
            #pragma unroll
            for (int i = 0; i < 8; ++i) {
                const int row = to * 8 + i;
                float wr = __shfl(wv, row, 64);   // lanes 0..31 hold rows 0..31
                union { uint2 u; _Float16 h[4]; } v;
                v.u = *(const uint2*)(bufc + row * ROWB + dq * 8);
                accA.x = fmaf(wr, (float)v.h[0], accA.x);
                accA.y = fmaf(wr, (float)v.h[1], accA.y);
                accA.z = fmaf(wr, (float)v.h[2], accA.z);
                accA.w = fmaf(wr, (float)v.h[3], accA.w);
            }
        }
        __syncthreads();                        // (C) bufc free for next top-write
    }

    // ---- cross-wave reduce over 'to' (4 row-octets), reusing dead A0 region ----
    float* pr = (float*)(smem + A0_OFF);       // [to][256] f32 = 4 KB
    {
        const int d0 = 4 * dq;
        pr[256*to + d0 + 0] = accA.x; pr[256*to + d0 + 1] = accA.y;
        pr[256*to + d0 + 2] = accA.z; pr[256*to + d0 + 3] = accA.w;
    }
    __syncthreads();
    {
        float v = pr[tid] + pr[256 + tid] + pr[512 + tid] + pr[768 + tid];
        size_t base = (size_t)bx * 258;
        part[base + tid] = v;
        if (tid == 0) part[base + 256] = mreg;
        if (tid == 1) part[base + 257] = lreg;
    }
}

__global__ __launch_bounds__(256)
void caa_combine(const float* __restrict__ part, float* __restrict__ out) {
    const int b = blockIdx.x, tid = threadIdx.x;
    __shared__ float sm[NT], sl[NT];
    if (tid < NT) {
        sm[tid] = part[(size_t)(b * NT + tid) * 258 + 256];
        sl[tid] = part[(size_t)(b * NT + tid) * 258 + 257];
    }
    __syncthreads();
    float M = sm[0];
    #pragma unroll
    for (int i = 1; i < NT; ++i) M = fmaxf(M, sm[i]);
    float S = 0.0f, o = 0.0f;
    #pragma unroll
    for (int i = 0; i < NT; ++i) {
        float e = __expf(sm[i] - M);
        S = fmaf(sl[i], e, S);
        o = fmaf(e, part[(size_t)(b * NT + i) * 258 + tid], o);
    }
    out[b * 256 + tid] = __fdividef(o, S);
}

extern "C" void kernel_launch(void* const* d_in, const int* in_sizes, int n_in,
                              void* d_out, int out_size, void* d_ws, size_t ws_size,
                              hipStream_t stream) {
    const float* seq = (const float*)d_in[0];
    const float* ctx = (const float*)d_in[1];
    const float* W1  = (const float*)d_in[2];
    const float* W2  = (const float*)d_in[3];
    float* part = (float*)d_ws;   // BB*NT*258*4 = 1,056,768 B of scratch

    caa_main<<<dim3(BB * NT), dim3(THREADS), 0, stream>>>(seq, ctx, W1, W2, part);
    caa_combine<<<dim3(BB), dim3(256), 0, stream>>>(part, (float*)d_out);
}

// Round 11
// 52.659 us; speedup vs baseline: 1.1779x; 1.1779x over previous
//
#include <hip/hip_runtime.h>
#include <cmath>

// Problem constants (fixed by the reference)
#define BB   64
#define TT   4096
#define DD1  256
#define DD2  128
#define UU   64
#define NT   16      // T tiles per batch row
#define TTILE 256    // rows per block
#define CH   32      // rows per chunk (staged in LDS)
#define NCH  8
#define THREADS 256

// A rows: 264 fp16 (=528 B): 256 data + 8 pad -> 4-dword bank rotation/row.
#define ROWB 528

// LDS byte offsets (static shared, 35.7 KB -> 4 blocks/CU at (256,4))
#define A0_OFF   0        // A buf0 [32][264] fp16 = 16896 B
#define A1_OFF   16896    // A buf1
#define BIAS_OFF 33792    // 64 f32
#define WCH_OFF  34048    // 32 f32 softmax weights
#define LOGP_OFF 34176    // 128 f32 logit partials (4 u-groups x 32 rows)
#define ML_OFF   34688    // [0]=m [1]=l [2]=rescale [3]=pad
#define RED_OFF  34704    // 256 f32 (bias partials)
#define LDS_BYTES 35728

typedef _Float16 fp16x8 __attribute__((ext_vector_type(8)));
typedef float    f32x4  __attribute__((ext_vector_type(4)));

__device__ __forceinline__ float tanh_fast(float x) {
    float ax = fabsf(x);
    float e  = __expf(-2.0f * ax);
    float t  = __fdividef(1.0f - e, 1.0f + e);
    return x < 0.0f ? -t : t;
}

// 8 f32 -> fp16x8 (RNE per element)
__device__ __forceinline__ fp16x8 cvt8(float4 a, float4 b) {
    fp16x8 v;
    v[0] = (_Float16)a.x; v[1] = (_Float16)a.y; v[2] = (_Float16)a.z; v[3] = (_Float16)a.w;
    v[4] = (_Float16)b.x; v[5] = (_Float16)b.y; v[6] = (_Float16)b.z; v[7] = (_Float16)b.w;
    return v;
}

__global__ __launch_bounds__(THREADS, 4)   // 4 waves/EU -> 4 blocks/CU, VGPR cap 128
void caa_main(const float* __restrict__ seq, const float* __restrict__ ctx,
              const float* __restrict__ W1, const float* __restrict__ W2,
              float* __restrict__ part) {
    __shared__ __align__(16) char smem[LDS_BYTES];
    float* fml   = (float*)(smem + ML_OFF);
    float* fbias = (float*)(smem + BIAS_OFF);
    float* fwch  = (float*)(smem + WCH_OFF);
    float* flogp = (float*)(smem + LOGP_OFF);
    float* fred  = (float*)(smem + RED_OFF);

    const int tid = threadIdx.x;
    const int bx  = blockIdx.x;
    const int b    = bx >> 4, tile = bx & 15;
    const int w    = tid >> 6, l = tid & 63;
    const int l15  = l & 15,  kg = l >> 4;     // MFMA input: row/col = l15, k-octet = kg
    const int s    = tid >> 5, q31 = tid & 31; // staging: row-slot s, dim-octet q31
    const int dq   = tid & 63, to = tid >> 6;  // accum: dim-quad dq, row-octet to (== w)

    const float* seqbase = seq + ((size_t)b * TT + (size_t)tile * TTILE) * DD1;

    // ---- chunk 0 global prefetch (8 float4 = 32 VGPR) ----
    // float4 idx f = j*512 + 2tid(+1) -> row 8j+s, floats 8q31..+7
    float4 pf[8];
    {
        const float4* g = (const float4*)seqbase;
        #pragma unroll
        for (int j = 0; j < 4; ++j) {
            pf[2*j]   = g[j*512 + 2*tid];
            pf[2*j+1] = g[j*512 + 2*tid + 1];
        }
    }

    // ---- B-frags (W1_seq, fp16): 1 u-group of 16 per wave, 32 VGPR ----
    const int u0g = w * 16 + l15;
    fp16x8 bf[8];
    #pragma unroll
    for (int ks = 0; ks < 8; ++ks) {
        const int kb = ks * 32 + kg * 8;
        float4 x0, x1;
        x0.x = W1[(kb+0)*UU + u0g]; x0.y = W1[(kb+1)*UU + u0g];
        x0.z = W1[(kb+2)*UU + u0g]; x0.w = W1[(kb+3)*UU + u0g];
        x1.x = W1[(kb+4)*UU + u0g]; x1.y = W1[(kb+5)*UU + u0g];
        x1.z = W1[(kb+6)*UU + u0g]; x1.w = W1[(kb+7)*UU + u0g];
        bf[ks] = cvt8(x0, x1);
    }

    // ---- bias partials: 4 c-chunks x 64 u ----
    {
        const int cq = tid >> 6;
        float sacc = 0.f;
        const float* cb = ctx + b * DD2 + cq * 32;
        const float* wb = W1 + (size_t)(DD1 + cq * 32) * UU + l;
        #pragma unroll
        for (int c = 0; c < 32; ++c) sacc = fmaf(cb[c], wb[c * UU], sacc);
        fred[cq * 64 + l] = sacc;
    }
    if (tid == 0) { fml[0] = -INFINITY; fml[1] = 0.f; }
    __syncthreads();
    if (tid < 64) {
        fbias[tid] = fred[tid] + fred[64 + tid] + fred[128 + tid] + fred[192 + tid];
    }
    // ---- chunk 0 -> A0 (fp16, b128 writes; compiler waits pf loads) ----
    #pragma unroll
    for (int j = 0; j < 4; ++j)
        *(fp16x8*)(smem + A0_OFF + (8*j + s) * ROWB + q31 * 16) = cvt8(pf[2*j], pf[2*j+1]);
    __syncthreads();

    const float bias0 = fbias[u0g];
    const float w20   = W2[u0g];
    const int aB0 = (     l15) * ROWB + kg * 16;   // m-frag 0 A byte base
    const int aB1 = (16 + l15) * ROWB + kg * 16;   // m-frag 1

    float4 accA = make_float4(0.f, 0.f, 0.f, 0.f); // dims 4dq..+3, rows to*8..+7 partial

    for (int c = 0; c < NCH; ++c) {
        const char* bufc = smem + ((c & 1) ? A1_OFF : A0_OFF);
        char*       bufn = smem + ((c & 1) ? A0_OFF : A1_OFF);
        // issue next-chunk loads; consumed at stage-write after barrier (B)
        if (c < NCH - 1) {
            const float4* g = (const float4*)(seqbase + (size_t)(c + 1) * CH * DD1);
            #pragma unroll
            for (int j = 0; j < 4; ++j) {
                pf[2*j]   = g[j*512 + 2*tid];
                pf[2*j+1] = g[j*512 + 2*tid + 1];
            }
        }
        // ---- fp16 MFMA GEMM: 32 rows x 16 u per wave, K=256, 16 MFMA ----
        f32x4 acc0 = {0.f,0.f,0.f,0.f}, acc1 = {0.f,0.f,0.f,0.f};
        #pragma unroll
        for (int ks = 0; ks < 8; ++ks) {
            fp16x8 ah0 = *(const fp16x8*)(bufc + aB0 + ks * 64);
            fp16x8 ah1 = *(const fp16x8*)(bufc + aB1 + ks * 64);
            acc0 = __builtin_amdgcn_mfma_f32_16x16x32_f16(ah0, bf[ks], acc0, 0, 0, 0);
            acc1 = __builtin_amdgcn_mfma_f32_16x16x32_f16(ah1, bf[ks], acc1, 0, 0, 0);
        }
        // ---- epilogue: tanh + W2 dot; reduce over the 16 u lanes ----
        float lp0[4], lp1[4];
        #pragma unroll
        for (int r = 0; r < 4; ++r) {
            float p0 = tanh_fast(acc0[r] + bias0) * w20;
            float p1 = tanh_fast(acc1[r] + bias0) * w20;
            p0 += __shfl_xor(p0, 1, 64);
            p1 += __shfl_xor(p1, 1, 64);
            p0 += __shfl_xor(p0, 2, 64);
            p1 += __shfl_xor(p1, 2, 64);
            p0 += __shfl_xor(p0, 4, 64);
            p1 += __shfl_xor(p1, 4, 64);
            p0 += __shfl_xor(p0, 8, 64);
            p1 += __shfl_xor(p1, 8, 64);
            lp0[r] = p0; lp1[r] = p1;
        }
        if (l15 == 0) {      // C/D row = kg*4 + r within m-frag (verified layout)
            #pragma unroll
            for (int r = 0; r < 4; ++r) {
                flogp[w * 32 +      kg * 4 + r] = lp0[r];
                flogp[w * 32 + 16 + kg * 4 + r] = lp1[r];
            }
        }
        __syncthreads();                        // (A) logit partials visible
        // ---- online softmax over 32 chunk rows (sum 4 u-group partials) ----
        if (tid < 32) {
            float lg = flogp[tid] + flogp[32 + tid] + flogp[64 + tid] + flogp[96 + tid];
            float mx = lg;
            mx = fmaxf(mx, __shfl_xor(mx, 1, 64));
            mx = fmaxf(mx, __shfl_xor(mx, 2, 64));
            mx = fmaxf(mx, __shfl_xor(mx, 4, 64));
            mx = fmaxf(mx, __shfl_xor(mx, 8, 64));
            mx = fmaxf(mx, __shfl_xor(mx, 16, 64));
            float mold = fml[0];
            float mnew = fmaxf(mold, mx);
            float rsc  = __expf(mold - mnew);   // first chunk: exp(-inf)=0
            float wv   = __expf(lg - mnew);
            float ss   = wv;
            ss += __shfl_xor(ss, 1, 64);
            ss += __shfl_xor(ss, 2, 64);
            ss += __shfl_xor(ss, 4, 64);
            ss += __shfl_xor(ss, 8, 64);
            ss += __shfl_xor(ss, 16, 64);
            fwch[tid] = wv;
            if (tid == 0) { fml[0] = mnew; fml[1] = fml[1] * rsc + ss; fml[2] = rsc; }
        }
        __syncthreads();                        // (B) weights visible
        // ---- stage next chunk into the OTHER buffer ----
        if (c < NCH - 1) {
            #pragma unroll
            for (int j = 0; j < 4; ++j)
                *(fp16x8*)(bufn + (8*j + s) * ROWB + q31 * 16) = cvt8(pf[2*j], pf[2*j+1]);
        }
        // ---- weighted accumulation from current fp16 tile ----
        {
            float rsc = fml[2];
            accA.x *= rsc; accA.y *= rsc; accA.z *= rsc; accA.w *= rsc;
            #pragma unroll
            for (int i = 0; i < 8; ++i) {
                const int row = to * 8 + i;
                float wr = fwch[row];
                union { uint2 u; _Float16 h[4]; } v;
                v.u = *(const uint2*)(bufc + row * ROWB + dq * 8);
                accA.x = fmaf(wr, (float)v.h[0], accA.x);
                accA.y = fmaf(wr, (float)v.h[1], accA.y);
                accA.z = fmaf(wr, (float)v.h[2], accA.z);
                accA.w = fmaf(wr, (float)v.h[3], accA.w);
            }
        }
        __syncthreads();                        // (C) next tile staged, iteration done
    }

    // ---- cross-wave reduce over 'to' (4 row-octets), reusing dead A0 region ----
    float* pr = (float*)(smem + A0_OFF);       // [to][256] f32 = 4 KB
    {
        const int d0 = 4 * dq;
        pr[256*to + d0 + 0] = accA.x; pr[256*to + d0 + 1] = accA.y;
        pr[256*to + d0 + 2] = accA.z; pr[256*to + d0 + 3] = accA.w;
    }
    __syncthreads();
    {
        float v = pr[tid] + pr[256 + tid] + pr[512 + tid] + pr[768 + tid];
        size_t base = (size_t)bx * 258;
        part[base + tid] = v;
        if (tid == 0) part[base + 256] = fml[0];
        if (tid == 1) part[base + 257] = fml[1];
    }
}

__global__ __launch_bounds__(256)
void caa_combine(const float* __restrict__ part, float* __restrict__ out) {
    const int b = blockIdx.x, tid = threadIdx.x;
    __shared__ float sm[NT], sl[NT];
    if (tid < NT) {
        sm[tid] = part[(size_t)(b * NT + tid) * 258 + 256];
        sl[tid] = part[(size_t)(b * NT + tid) * 258 + 257];
    }
    __syncthreads();
    float M = sm[0];
    #pragma unroll
    for (int i = 1; i < NT; ++i) M = fmaxf(M, sm[i]);
    float S = 0.0f, o = 0.0f;
    #pragma unroll
    for (int i = 0; i < NT; ++i) {
        float e = __expf(sm[i] - M);
        S = fmaf(sl[i], e, S);
        o = fmaf(e, part[(size_t)(b * NT + i) * 258 + tid], o);
    }
    out[b * 256 + tid] = __fdividef(o, S);
}

extern "C" void kernel_launch(void* const* d_in, const int* in_sizes, int n_in,
                              void* d_out, int out_size, void* d_ws, size_t ws_size,
                              hipStream_t stream) {
    const float* seq = (const float*)d_in[0];
    const float* ctx = (const float*)d_in[1];
    const float* W1  = (const float*)d_in[2];
    const float* W2  = (const float*)d_in[3];
    float* part = (float*)d_ws;   // BB*NT*258*4 = 1,056,768 B of scratch

    caa_main<<<dim3(BB * NT), dim3(THREADS), 0, stream>>>(seq, ctx, W1, W2, part);
    caa_combine<<<dim3(BB), dim3(256), 0, stream>>>(part, (float*)d_out);
}